// Round 1
// baseline (162.514 us; speedup 1.0000x reference)
//
#include <hip/hip_runtime.h>
#include <stdint.h>

#define Tn 1024
#define En 1024
#define Bn 4
#define Hn 16

typedef __bf16 v8bf __attribute__((ext_vector_type(8)));
typedef float  v4f  __attribute__((ext_vector_type(4)));

__device__ __forceinline__ uint16_t f2bf(float f){
  union { float f; uint32_t u; } v; v.f = f;
  uint32_t r = v.u + 0x7FFFu + ((v.u >> 16) & 1u);
  return (uint16_t)(r >> 16);
}

__device__ __forceinline__ v4f vzero(){ v4f z = {0.f,0.f,0.f,0.f}; return z; }

// stage a 128x64 bf16 tile (global, row stride ldg elems) into LDS with row stride 72
__device__ __forceinline__ void stage_tile(uint16_t* __restrict__ s,
                                           const uint16_t* __restrict__ g,
                                           int ldg, int tid){
  int r0 = tid >> 3;            // 0..31
  int c8 = (tid & 7) * 8;       // 0..56
  #pragma unroll
  for (int c = 0; c < 4; ++c){
    int row = r0 + c * 32;
    *(uint4*)(s + row * 72 + c8) = *(const uint4*)(g + (size_t)row * ldg + c8);
  }
}

// stage V[128 j][64 d] transposed into Vt[d][j], LDS row stride 136
__device__ __forceinline__ void stage_vt(uint16_t* __restrict__ s,
                                         const uint16_t* __restrict__ g, int tid){
  int j  = tid >> 1;            // 0..127
  int d0 = (tid & 1) * 32;      // 0 or 32
  union { uint4 v[4]; uint16_t h[32]; } t;
  #pragma unroll
  for (int c = 0; c < 4; ++c)
    t.v[c] = *(const uint4*)(g + (size_t)j * En + d0 + c * 8);
  #pragma unroll
  for (int e = 0; e < 32; ++e)
    s[(d0 + e) * 136 + j] = t.h[e];
}

// ---------------- prep kernels ----------------

__global__ void k_xcast(const float* __restrict__ X, uint16_t* __restrict__ Xb){
  int i = (blockIdx.x * 256 + threadIdx.x) * 8;
  float4 a = *(const float4*)(X + i);
  float4 b = *(const float4*)(X + i + 4);
  union { uint16_t h[8]; uint4 v; } o;
  o.h[0]=f2bf(a.x); o.h[1]=f2bf(a.y); o.h[2]=f2bf(a.z); o.h[3]=f2bf(a.w);
  o.h[4]=f2bf(b.x); o.h[5]=f2bf(b.y); o.h[6]=f2bf(b.z); o.h[7]=f2bf(b.w);
  *(uint4*)(Xb + i) = o.v;
}

// W_eff[f,k] = W[f,k] + sum_r B[f,r]*A[r,k]   (bias handled in GEMM epilogue)
__global__ void k_weff(const float* __restrict__ W, const float* __restrict__ A,
                       const float* __restrict__ Bm, uint16_t* __restrict__ Wo){
  int idx = blockIdx.x * 256 + threadIdx.x;   // over 1024*1024
  int f = idx >> 10, k = idx & 1023;
  float acc = W[idx];
  #pragma unroll
  for (int r = 0; r < 16; ++r) acc += Bm[f * 16 + r] * A[r * 1024 + k];
  Wo[idx] = f2bf(acc);
}

// ---------------- projection GEMM ----------------
// C[m,f] = sum_k A[m,k]*B[f,k] + bias[f]; A,B row-major [.,1024] bf16; C bf16 row-major
__global__ __launch_bounds__(256)
void k_gemm(const uint16_t* __restrict__ Ag, const uint16_t* __restrict__ Bg,
            const float* __restrict__ bias, uint16_t* __restrict__ Cg){
  __shared__ __align__(16) uint16_t As[128 * 72];
  __shared__ __align__(16) uint16_t Bs[128 * 72];
  int tid = threadIdx.x;
  int lane = tid & 63, wid = tid >> 6;
  int l15 = lane & 15, lg = lane >> 4;
  int wr = wid >> 1, wc = wid & 1;
  int m0 = blockIdx.x * 128, n0 = blockIdx.y * 128;
  v4f acc[4][4];
  #pragma unroll
  for (int a = 0; a < 4; ++a)
    #pragma unroll
    for (int c = 0; c < 4; ++c) acc[a][c] = vzero();

  for (int kk = 0; kk < En; kk += 64){
    stage_tile(As, Ag + (size_t)m0 * En + kk, En, tid);
    stage_tile(Bs, Bg + (size_t)n0 * En + kk, En, tid);
    __syncthreads();
    #pragma unroll
    for (int kc = 0; kc < 2; ++kc){
      v8bf af[4], bfv[4];
      #pragma unroll
      for (int mi = 0; mi < 4; ++mi)
        af[mi] = *(const v8bf*)(As + (wr * 64 + mi * 16 + l15) * 72 + kc * 32 + lg * 8);
      #pragma unroll
      for (int nj = 0; nj < 4; ++nj)
        bfv[nj] = *(const v8bf*)(Bs + (wc * 64 + nj * 16 + l15) * 72 + kc * 32 + lg * 8);
      #pragma unroll
      for (int mi = 0; mi < 4; ++mi)
        #pragma unroll
        for (int nj = 0; nj < 4; ++nj)
          acc[mi][nj] = __builtin_amdgcn_mfma_f32_16x16x32_bf16(af[mi], bfv[nj], acc[mi][nj], 0, 0, 0);
    }
    __syncthreads();
  }
  #pragma unroll
  for (int nj = 0; nj < 4; ++nj){
    int n = n0 + wc * 64 + nj * 16 + l15;
    float bv = bias[n];
    #pragma unroll
    for (int mi = 0; mi < 4; ++mi){
      #pragma unroll
      for (int r = 0; r < 4; ++r){
        int m = m0 + wr * 64 + mi * 16 + lg * 4 + r;
        Cg[(size_t)m * En + n] = f2bf(acc[mi][nj][r] + bv);
      }
    }
  }
}

// ---------------- attention pass 1: column sums ----------------
// csum[bh, j] = sum_{i >= j} exp(q_i . k_j / 32)
__global__ __launch_bounds__(256)
void k_colsum(const uint16_t* __restrict__ Qg, const uint16_t* __restrict__ Kg,
              float* __restrict__ csum){
  int jt = blockIdx.x, bh = blockIdx.y;
  int b = bh >> 4, h = bh & 15;
  __shared__ __align__(16) uint16_t Qs[128 * 72];
  __shared__ __align__(16) uint16_t Ks[128 * 72];
  __shared__ float colacc[128];
  int tid = threadIdx.x, lane = tid & 63, wid = tid >> 6;
  int l15 = lane & 15, lg = lane >> 4;
  int wr = wid >> 1, wc = wid & 1;
  size_t base = ((size_t)b * Tn) * En + h * 64;
  int j0 = jt * 128;
  stage_tile(Ks, Kg + base + (size_t)j0 * En, En, tid);
  if (tid < 128) colacc[tid] = 0.f;
  __syncthreads();
  float cp[4] = {0.f, 0.f, 0.f, 0.f};
  for (int it = jt; it < 8; ++it){
    int i0 = it * 128;
    stage_tile(Qs, Qg + base + (size_t)i0 * En, En, tid);
    __syncthreads();
    v4f acc[4][4];
    #pragma unroll
    for (int a = 0; a < 4; ++a)
      #pragma unroll
      for (int c = 0; c < 4; ++c) acc[a][c] = vzero();
    #pragma unroll
    for (int kc = 0; kc < 2; ++kc){
      v8bf af[4], bfv[4];
      #pragma unroll
      for (int mi = 0; mi < 4; ++mi)
        af[mi] = *(const v8bf*)(Qs + (wr * 64 + mi * 16 + l15) * 72 + kc * 32 + lg * 8);
      #pragma unroll
      for (int nj = 0; nj < 4; ++nj)
        bfv[nj] = *(const v8bf*)(Ks + (wc * 64 + nj * 16 + l15) * 72 + kc * 32 + lg * 8);
      #pragma unroll
      for (int mi = 0; mi < 4; ++mi)
        #pragma unroll
        for (int nj = 0; nj < 4; ++nj)
          acc[mi][nj] = __builtin_amdgcn_mfma_f32_16x16x32_bf16(af[mi], bfv[nj], acc[mi][nj], 0, 0, 0);
    }
    #pragma unroll
    for (int nj = 0; nj < 4; ++nj){
      int jg = j0 + wc * 64 + nj * 16 + l15;
      #pragma unroll
      for (int mi = 0; mi < 4; ++mi){
        #pragma unroll
        for (int r = 0; r < 4; ++r){
          int ig = i0 + wr * 64 + mi * 16 + lg * 4 + r;
          float e = (jg <= ig) ? __expf(acc[mi][nj][r] * 0.03125f) : 0.f;
          cp[nj] += e;
        }
      }
    }
    __syncthreads();
  }
  #pragma unroll
  for (int nj = 0; nj < 4; ++nj){
    float v = cp[nj];
    v += __shfl_xor(v, 16, 64);
    v += __shfl_xor(v, 32, 64);
    if (lane < 16) atomicAdd(&colacc[wc * 64 + nj * 16 + l15], v);
  }
  __syncthreads();
  if (tid < 128) csum[(size_t)bh * Tn + j0 + tid] = colacc[tid];
}

// ---------------- attention pass 2: P@V with column-normalized P ----------------
__global__ __launch_bounds__(256)
void k_attnout(const uint16_t* __restrict__ Qg, const uint16_t* __restrict__ Kg,
               const uint16_t* __restrict__ Vg, const float* __restrict__ csum,
               const float* __restrict__ mask, float* __restrict__ out){
  int it = blockIdx.x, bh = blockIdx.y;
  int b = bh >> 4, h = bh & 15;
  __shared__ __align__(16) uint16_t Qs[128 * 72];
  __shared__ __align__(16) uint16_t KP[128 * 136];   // K tile (stride 72), then P tile (stride 136)
  __shared__ __align__(16) uint16_t Vt[64 * 136];    // V transposed [d][j]
  __shared__ float scb[128];
  int tid = threadIdx.x, lane = tid & 63, wid = tid >> 6;
  int l15 = lane & 15, lg = lane >> 4;
  int wr = wid >> 1, wc = wid & 1;
  size_t base = ((size_t)b * Tn) * En + h * 64;
  int i0 = it * 128;
  stage_tile(Qs, Qg + base + (size_t)i0 * En, En, tid);
  v4f oacc[2][4];
  #pragma unroll
  for (int a = 0; a < 2; ++a)
    #pragma unroll
    for (int c = 0; c < 4; ++c) oacc[a][c] = vzero();

  for (int jt = 0; jt <= it; ++jt){
    int j0 = jt * 128;
    stage_tile(KP, Kg + base + (size_t)j0 * En, En, tid);
    stage_vt(Vt, Vg + base + (size_t)j0 * En, tid);
    if (tid < 128)
      scb[tid] = mask[b * Tn + j0 + tid] / csum[(size_t)bh * Tn + j0 + tid];
    __syncthreads();
    // S^T tile: A = K rows (j), B = Q rows (i) -> C[j][i]; col=i=l15, row=j=lg*4+r
    v4f sacc[4][4];
    #pragma unroll
    for (int a = 0; a < 4; ++a)
      #pragma unroll
      for (int c = 0; c < 4; ++c) sacc[a][c] = vzero();
    #pragma unroll
    for (int kc = 0; kc < 2; ++kc){
      v8bf af[4], bq[4];
      #pragma unroll
      for (int mj = 0; mj < 4; ++mj)
        af[mj] = *(const v8bf*)(KP + (wr * 64 + mj * 16 + l15) * 72 + kc * 32 + lg * 8);
      #pragma unroll
      for (int ni = 0; ni < 4; ++ni)
        bq[ni] = *(const v8bf*)(Qs + (wc * 64 + ni * 16 + l15) * 72 + kc * 32 + lg * 8);
      #pragma unroll
      for (int mj = 0; mj < 4; ++mj)
        #pragma unroll
        for (int ni = 0; ni < 4; ++ni)
          sacc[mj][ni] = __builtin_amdgcn_mfma_f32_16x16x32_bf16(af[mj], bq[ni], sacc[mj][ni], 0, 0, 0);
    }
    __syncthreads();   // everyone done reading KP as K-tile
    // P[i][j] = exp(S/32) * mask_j / colsum_j  (0 where j > i), written stride 136
    #pragma unroll
    for (int mj = 0; mj < 4; ++mj){
      int jb = wr * 64 + mj * 16 + lg * 4;       // j base for regs 0..3
      v4f sc4 = *(const v4f*)(scb + jb);
      #pragma unroll
      for (int ni = 0; ni < 4; ++ni){
        int il = wc * 64 + ni * 16 + l15;
        int ig = i0 + il;
        float e0 = (j0 + jb + 0 <= ig) ? __expf(sacc[mj][ni][0] * 0.03125f) * sc4[0] : 0.f;
        float e1 = (j0 + jb + 1 <= ig) ? __expf(sacc[mj][ni][1] * 0.03125f) * sc4[1] : 0.f;
        float e2 = (j0 + jb + 2 <= ig) ? __expf(sacc[mj][ni][2] * 0.03125f) * sc4[2] : 0.f;
        float e3 = (j0 + jb + 3 <= ig) ? __expf(sacc[mj][ni][3] * 0.03125f) * sc4[3] : 0.f;
        uint2 pk;
        pk.x = (uint32_t)f2bf(e0) | ((uint32_t)f2bf(e1) << 16);
        pk.y = (uint32_t)f2bf(e2) | ((uint32_t)f2bf(e3) << 16);
        *(uint2*)(KP + il * 136 + jb) = pk;
      }
    }
    __syncthreads();
    // PV: each wave computes out rows [wid*32, wid*32+32)
    #pragma unroll
    for (int kc = 0; kc < 4; ++kc){
      v8bf pa[2], vb[4];
      #pragma unroll
      for (int mi2 = 0; mi2 < 2; ++mi2)
        pa[mi2] = *(const v8bf*)(KP + (wid * 32 + mi2 * 16 + l15) * 136 + kc * 32 + lg * 8);
      #pragma unroll
      for (int dj = 0; dj < 4; ++dj)
        vb[dj] = *(const v8bf*)(Vt + (dj * 16 + l15) * 136 + kc * 32 + lg * 8);
      #pragma unroll
      for (int mi2 = 0; mi2 < 2; ++mi2)
        #pragma unroll
        for (int dj = 0; dj < 4; ++dj)
          oacc[mi2][dj] = __builtin_amdgcn_mfma_f32_16x16x32_bf16(pa[mi2], vb[dj], oacc[mi2][dj], 0, 0, 0);
    }
    __syncthreads();
  }
  #pragma unroll
  for (int mi2 = 0; mi2 < 2; ++mi2)
    #pragma unroll
    for (int dj = 0; dj < 4; ++dj)
      #pragma unroll
      for (int r = 0; r < 4; ++r){
        int ig = i0 + wid * 32 + mi2 * 16 + lg * 4 + r;
        int d  = dj * 16 + l15;
        out[((size_t)(b * Tn) + ig) * En + h * 64 + d] = oacc[mi2][dj][r];
      }
}

extern "C" void kernel_launch(void* const* d_in, const int* in_sizes, int n_in,
                              void* d_out, int out_size, void* d_ws, size_t ws_size,
                              hipStream_t stream) {
  (void)in_sizes; (void)n_in; (void)out_size; (void)ws_size;
  const float* X    = (const float*)d_in[0];
  const float* mask = (const float*)d_in[1];
  const float* Wq   = (const float*)d_in[2];
  const float* bq   = (const float*)d_in[3];
  const float* Wk   = (const float*)d_in[4];
  const float* bk   = (const float*)d_in[5];
  const float* Wv   = (const float*)d_in[6];
  const float* bv   = (const float*)d_in[7];
  const float* Aq   = (const float*)d_in[8];
  const float* Bq   = (const float*)d_in[9];
  const float* Ak   = (const float*)d_in[10];
  const float* Bk   = (const float*)d_in[11];
  const float* Av   = (const float*)d_in[12];
  const float* Bv   = (const float*)d_in[13];
  float* out = (float*)d_out;

  uint16_t* Xb   = (uint16_t*)d_ws;                    // [4096][1024] bf16
  uint16_t* Weff = Xb + (size_t)4096 * 1024;           // 3 x [1024][1024] bf16
  uint16_t* QKV  = Weff + (size_t)3 * 1024 * 1024;     // 3 x [4096][1024] bf16
  float*    csum = (float*)(QKV + (size_t)3 * 4096 * 1024); // [64][1024] f32

  k_xcast<<<2048, 256, 0, stream>>>(X, Xb);
  k_weff<<<4096, 256, 0, stream>>>(Wq, Aq, Bq, Weff);
  k_weff<<<4096, 256, 0, stream>>>(Wk, Ak, Bk, Weff + 1048576);
  k_weff<<<4096, 256, 0, stream>>>(Wv, Av, Bv, Weff + 2097152);

  dim3 gg(32, 8);
  k_gemm<<<gg, 256, 0, stream>>>(Xb, Weff,           bq, QKV);
  k_gemm<<<gg, 256, 0, stream>>>(Xb, Weff + 1048576, bk, QKV + 4194304);
  k_gemm<<<gg, 256, 0, stream>>>(Xb, Weff + 2097152, bv, QKV + 8388608);

  dim3 ga(8, 64);
  k_colsum<<<ga, 256, 0, stream>>>(QKV, QKV + 4194304, csum);
  k_attnout<<<ga, 256, 0, stream>>>(QKV, QKV + 4194304, QKV + 8388608, csum, mask, out);
}